// Round 2
// baseline (114.498 us; speedup 1.0000x reference)
//
#include <hip/hip_runtime.h>

#define NMAX 10
#define KPL 16          // hidden units per lane (1024 / 64)

// ---------- DPP cross-lane sum (all VALU pipe, no LDS) ----------
template<int CTRL, int RMASK, int BMASK>
__device__ __forceinline__ float dppmov(float v) {
    return __int_as_float(__builtin_amdgcn_update_dpp(
        0, __float_as_int(v), CTRL, RMASK, BMASK, true));
}
__device__ __forceinline__ float rdlane63(float v) {
    return __int_as_float(__builtin_amdgcn_readlane(__float_as_int(v), 63));
}

// wave64 sum -> uniform (via SGPR broadcast). Two independent chains for ILP.
__device__ __forceinline__ void wred2(float& a, float& b) {
    a += dppmov<0xB1, 0xf, 0xf>(a);  b += dppmov<0xB1, 0xf, 0xf>(b);  // xor1 (quad_perm 1,0,3,2)
    a += dppmov<0x4E, 0xf, 0xf>(a);  b += dppmov<0x4E, 0xf, 0xf>(b);  // xor2 (quad_perm 2,3,0,1)
    a += dppmov<0x141,0xf, 0xf>(a);  b += dppmov<0x141,0xf, 0xf>(b);  // xor4 (half mirror; quad-uniform)
    a += dppmov<0x140,0xf, 0xf>(a);  b += dppmov<0x140,0xf, 0xf>(b);  // xor8 (mirror; 8-uniform)
    a += dppmov<0x142,0xa, 0xf>(a);  b += dppmov<0x142,0xa, 0xf>(b);  // row_bcast15 -> rows 1,3
    a += dppmov<0x143,0xc, 0xf>(a);  b += dppmov<0x143,0xc, 0xf>(b);  // row_bcast31 -> rows 2,3
    a = rdlane63(a);                 b = rdlane63(b);
}
__device__ __forceinline__ float wred1(float a) {
    a += dppmov<0xB1, 0xf, 0xf>(a);
    a += dppmov<0x4E, 0xf, 0xf>(a);
    a += dppmov<0x141,0xf, 0xf>(a);
    a += dppmov<0x140,0xf, 0xf>(a);
    a += dppmov<0x142,0xa, 0xf>(a);
    a += dppmov<0x143,0xc, 0xf>(a);
    return rdlane63(a);
}

__device__ __forceinline__ float elu_f(float p) {
    // jax.nn.elu: p>0 ? p : expm1(p); select discards the unused path.
    return p > 0.f ? p : (__expf(p) - 1.f);
}

// two samples' MLP evals interleaved (shared wy/w2 registers)
__device__ __forceinline__ void mlp2(const float (&wy)[KPL], const float (&uA)[KPL],
                                     const float (&uB)[KPL], const float (&w2)[KPL],
                                     float yA, float yB, float bias,
                                     float& oA, float& oB)
{
    float a0 = 0.f, a1 = 0.f, b0 = 0.f, b1 = 0.f;
#pragma unroll
    for (int k = 0; k < KPL; k += 2) {
        a0 = fmaf(w2[k],     elu_f(fmaf(wy[k],     yA, uA[k])),     a0);
        b0 = fmaf(w2[k],     elu_f(fmaf(wy[k],     yB, uB[k])),     b0);
        a1 = fmaf(w2[k + 1], elu_f(fmaf(wy[k + 1], yA, uA[k + 1])), a1);
        b1 = fmaf(w2[k + 1], elu_f(fmaf(wy[k + 1], yB, uB[k + 1])), b1);
    }
    float a = a0 + a1, b = b0 + b1;
    wred2(a, b);
    oA = a + bias; oB = b + bias;
}

__device__ __forceinline__ float mlp1(const float (&wy)[KPL], const float (&u)[KPL],
                                      const float (&w2)[KPL], float y, float bias)
{
    float a0 = 0.f, a1 = 0.f, a2 = 0.f, a3 = 0.f;
#pragma unroll
    for (int k = 0; k < KPL; k += 4) {
        a0 = fmaf(w2[k + 0], elu_f(fmaf(wy[k + 0], y, u[k + 0])), a0);
        a1 = fmaf(w2[k + 1], elu_f(fmaf(wy[k + 1], y, u[k + 1])), a1);
        a2 = fmaf(w2[k + 2], elu_f(fmaf(wy[k + 2], y, u[k + 2])), a2);
        a3 = fmaf(w2[k + 3], elu_f(fmaf(wy[k + 3], y, u[k + 3])), a3);
    }
    return wred1((a0 + a1) + (a2 + a3)) + bias;
}

__global__ __launch_bounds__(256) void rmodel_kernel(
    const float* __restrict__ X, const float* __restrict__ Y,
    const float* __restrict__ de_W1, const float* __restrict__ de_b1,
    const float* __restrict__ de_W2, const float* __restrict__ de_b2,
    const float* __restrict__ val_W1, const float* __restrict__ val_b1,
    const float* __restrict__ val_W2, const float* __restrict__ val_b2,
    float* __restrict__ out, int n)
{
    const int wid  = threadIdx.x >> 6;
    const int lane = threadIdx.x & 63;
    const int half = (n + 1) >> 1;
    const int p    = blockIdx.x * 4 + wid;
    if (p >= half) return;
    const int bA = p, bB = p + half;
    const bool hasB = (bB < n);

    float dwy[KPL], duA[KPL], duB[KPL], dw2[KPL];
    float vwy[KPL], vuA[KPL], vuB[KPL], vw2[KPL];

    const float xA = X[bA];
    const float xB = hasB ? X[bB] : 0.f;
    float yA = Y[bA];
    float yB = hasB ? Y[bB] : 0.f;

#pragma unroll
    for (int k = 0; k < KPL; ++k) {
        const int h = k * 64 + lane;
        float2 w1d = reinterpret_cast<const float2*>(de_W1)[h];
        dwy[k] = w1d.y;
        const float b1d = de_b1[h];
        duA[k] = fmaf(w1d.x, xA, b1d);          // hoist: u = w0*x + b1
        duB[k] = fmaf(w1d.x, xB, b1d);
        dw2[k] = de_W2[h];
        float2 w1v = reinterpret_cast<const float2*>(val_W1)[h];
        vwy[k] = w1v.y;
        const float b1v = val_b1[h];
        vuA[k] = fmaf(w1v.x, xA, b1v);
        vuB[k] = fmaf(w1v.x, xB, b1v);
        vw2[k] = val_W2[h];
    }
    const float db2 = de_b2[0], vb2 = val_b2[0];

    float* __restrict__ yout = out;                      // [NMAX+1][n]
    float* __restrict__ vout = out + (size_t)(NMAX + 1) * n;

    // ---- v0 for both samples ----
    float vpA, vpB;
    mlp2(vwy, vuA, vuB, vw2, yA, yB, vb2, vpA, vpB);
    if (lane == 0) {
        yout[bA] = yA; vout[bA] = vpA;
        if (hasB) { yout[bB] = yB; vout[bB] = vpB; }
    }

    int t = 0, eA = 0, eB = 0;
    bool actA = true, actB = hasB;

    // ---- joint phase: both chains interleaved (2x ILP) ----
    while (t < NMAX && actA && actB) {
        float dA, dB;
        mlp2(dwy, duA, duB, dw2, yA, yB, db2, dA, dB);
        const float ynA = yA + dA, ynB = yB + dB;
        float vnA, vnB;
        mlp2(vwy, vuA, vuB, vw2, ynA, ynB, vb2, vnA, vnB);
        if (lane == 0) {
            yout[(size_t)(t + 1) * n + bA] = ynA; vout[(size_t)(t + 1) * n + bA] = vnA;
            yout[(size_t)(t + 1) * n + bB] = ynB; vout[(size_t)(t + 1) * n + bB] = vnB;
        }
        const bool brkA = (t > 0) && (vnA >= vpA);
        const bool brkB = (t > 0) && (vnB >= vpB);
        yA = ynA; vpA = vnA; yB = ynB; vpB = vnB;
        ++t; eA = t; eB = t;
        actA = !brkA; actB = !brkB;
    }
    // ---- tail: at most one sample still active ----
    while (t < NMAX && actA) {
        const float d  = mlp1(dwy, duA, dw2, yA, db2);
        const float yn = yA + d;
        const float vn = mlp1(vwy, vuA, vw2, yn, vb2);
        if (lane == 0) {
            yout[(size_t)(t + 1) * n + bA] = yn; vout[(size_t)(t + 1) * n + bA] = vn;
        }
        const bool brk = (t > 0) && (vn >= vpA);
        yA = yn; vpA = vn; ++t; eA = t;
        if (brk) actA = false;
    }
    while (t < NMAX && actB) {
        const float d  = mlp1(dwy, duB, dw2, yB, db2);
        const float yn = yB + d;
        const float vn = mlp1(vwy, vuB, vw2, yn, vb2);
        if (lane == 0) {
            yout[(size_t)(t + 1) * n + bB] = yn; vout[(size_t)(t + 1) * n + bB] = vn;
        }
        const bool brk = (t > 0) && (vn >= vpB);
        yB = yn; vpB = vn; ++t; eB = t;
        if (brk) actB = false;
    }

    // ---- fill frozen rows ----
    if (lane == 0) {
        for (int j = eA + 1; j <= NMAX; ++j) {
            yout[(size_t)j * n + bA] = yA; vout[(size_t)j * n + bA] = vpA;
        }
        if (hasB) {
            for (int j = eB + 1; j <= NMAX; ++j) {
                yout[(size_t)j * n + bB] = yB; vout[(size_t)j * n + bB] = vpB;
            }
        }
    }
}

extern "C" void kernel_launch(void* const* d_in, const int* in_sizes, int n_in,
                              void* d_out, int out_size, void* d_ws, size_t ws_size,
                              hipStream_t stream) {
    const float* X      = (const float*)d_in[0];
    const float* Y      = (const float*)d_in[1];
    const float* de_W1  = (const float*)d_in[2];
    const float* de_b1  = (const float*)d_in[3];
    const float* de_W2  = (const float*)d_in[4];
    const float* de_b2  = (const float*)d_in[5];
    const float* val_W1 = (const float*)d_in[6];
    const float* val_b1 = (const float*)d_in[7];
    const float* val_W2 = (const float*)d_in[8];
    const float* val_b2 = (const float*)d_in[9];
    float* out = (float*)d_out;

    const int n    = in_sizes[0];            // 16384 samples
    const int half = (n + 1) >> 1;           // sample pairs per wave
    dim3 block(256);                          // 4 waves/block, 1 wave = 2 samples
    dim3 grid((half + 3) / 4);
    hipLaunchKernelGGL(rmodel_kernel, grid, block, 0, stream,
                       X, Y, de_W1, de_b1, de_W2, de_b2,
                       val_W1, val_b1, val_W2, val_b2, out, n);
}

// Round 3
// 84.641 us; speedup vs baseline: 1.3527x; 1.3527x over previous
//
#include <hip/hip_runtime.h>

#define NMAX 10
#define KPL  16          // hidden units per lane (1024 / 64)
#define L2E  1.4426950408889634f

// ---------- DPP cross-lane sum (VALU pipe only) ----------
template<int CTRL, int RMASK, int BMASK>
__device__ __forceinline__ float dppmov(float v) {
    return __int_as_float(__builtin_amdgcn_update_dpp(
        0, __float_as_int(v), CTRL, RMASK, BMASK, true));
}
__device__ __forceinline__ float rdlane63(float v) {
    return __int_as_float(__builtin_amdgcn_readlane(__float_as_int(v), 63));
}

// two independent wave64 sums -> uniform scalars (2 chains for ILP)
__device__ __forceinline__ void wred2(float& a, float& b) {
    a += dppmov<0xB1, 0xf, 0xf>(a);  b += dppmov<0xB1, 0xf, 0xf>(b);  // quad xor1
    a += dppmov<0x4E, 0xf, 0xf>(a);  b += dppmov<0x4E, 0xf, 0xf>(b);  // quad xor2
    a += dppmov<0x141,0xf, 0xf>(a);  b += dppmov<0x141,0xf, 0xf>(b);  // half-row mirror
    a += dppmov<0x140,0xf, 0xf>(a);  b += dppmov<0x140,0xf, 0xf>(b);  // row mirror
    a += dppmov<0x142,0xa, 0xf>(a);  b += dppmov<0x142,0xa, 0xf>(b);  // row_bcast15
    a += dppmov<0x143,0xc, 0xf>(a);  b += dppmov<0x143,0xc, 0xf>(b);  // row_bcast31
    a = rdlane63(a);                 b = rdlane63(b);
}
__device__ __forceinline__ float wred1(float a) {
    a += dppmov<0xB1, 0xf, 0xf>(a);
    a += dppmov<0x4E, 0xf, 0xf>(a);
    a += dppmov<0x141,0xf, 0xf>(a);
    a += dppmov<0x140,0xf, 0xf>(a);
    a += dppmov<0x142,0xa, 0xf>(a);
    a += dppmov<0x143,0xc, 0xf>(a);
    return rdlane63(a);
}

// elu(p) = s(p) - 1,  s = (p>0 ? p+1 : exp(p)).
// With u1 = u+1 pre-hoisted: p1 = fma(wy,y,u1) = p+1, s = (p1>1 ? p1 : exp2((p1-1)*L2E)).
// The "-1" is folded into the output bias as  bias' = b2 - sum_h(w2[h]).
__device__ __forceinline__ float sact(float p1) {
    float e = __builtin_amdgcn_exp2f(fmaf(p1, L2E, -L2E));
    return p1 > 1.f ? p1 : e;
}

// joint eval of BOTH MLPs at the same y (2 independent chains of 16 units)
__device__ __forceinline__ void mlp_joint(
    const float (&dwy)[KPL], const float (&du1)[KPL], const float (&dw2)[KPL],
    const float (&vwy)[KPL], const float (&vu1)[KPL], const float (&vw2)[KPL],
    float y, float dbias, float vbias, float& dout, float& vout)
{
    float a0 = 0.f, a1 = 0.f, b0 = 0.f, b1 = 0.f;
#pragma unroll
    for (int k = 0; k < KPL; k += 2) {
        float pd0 = fmaf(dwy[k],     y, du1[k]);
        float pv0 = fmaf(vwy[k],     y, vu1[k]);
        float pd1 = fmaf(dwy[k + 1], y, du1[k + 1]);
        float pv1 = fmaf(vwy[k + 1], y, vu1[k + 1]);
        a0 = fmaf(dw2[k],     sact(pd0), a0);
        b0 = fmaf(vw2[k],     sact(pv0), b0);
        a1 = fmaf(dw2[k + 1], sact(pd1), a1);
        b1 = fmaf(vw2[k + 1], sact(pv1), b1);
    }
    float a = a0 + a1, b = b0 + b1;
    wred2(a, b);
    dout = a + dbias; vout = b + vbias;
}

__global__ __launch_bounds__(64, 4) void rmodel_kernel(
    const float* __restrict__ X, const float* __restrict__ Y,
    const float* __restrict__ de_W1, const float* __restrict__ de_b1,
    const float* __restrict__ de_W2, const float* __restrict__ de_b2,
    const float* __restrict__ val_W1, const float* __restrict__ val_b1,
    const float* __restrict__ val_W2, const float* __restrict__ val_b2,
    float* __restrict__ out, int n)
{
    const int lane = threadIdx.x & 63;
    const int b    = blockIdx.x;          // one wave per sample
    if (b >= n) return;

    float dwy[KPL], du1[KPL], dw2[KPL];
    float vwy[KPL], vu1[KPL], vw2[KPL];

    const float x = X[b];
    const float y0 = Y[b];

    float sw_d = 0.f, sw_v = 0.f;         // sum of W2 (for the folded -1)
#pragma unroll
    for (int k = 0; k < KPL; ++k) {
        const int h = k * 64 + lane;
        float2 w1d = reinterpret_cast<const float2*>(de_W1)[h];
        dwy[k] = w1d.y;
        du1[k] = fmaf(w1d.x, x, de_b1[h]) + 1.f;   // u + 1
        dw2[k] = de_W2[h];   sw_d += dw2[k];
        float2 w1v = reinterpret_cast<const float2*>(val_W1)[h];
        vwy[k] = w1v.y;
        vu1[k] = fmaf(w1v.x, x, val_b1[h]) + 1.f;
        vw2[k] = val_W2[h];  sw_v += vw2[k];
    }
    const float db2 = de_b2[0]  - wred1(sw_d);     // bias' = b2 - sum(w2)
    const float vb2 = val_b2[0] - wred1(sw_v);

    float* __restrict__ yout = out;                       // [NMAX+1][n]
    float* __restrict__ vout = out + (size_t)(NMAX + 1) * n;

    // ---- pipelined chain: each step jointly computes val(y_k) and de(y_k) ----
    float d, v;
    mlp_joint(dwy, du1, dw2, vwy, vu1, vw2, y0, db2, vb2, d, v);   // d0, v0
    if (lane == 0) { yout[b] = y0; vout[b] = v; }

    float y     = y0 + d;     // y1
    float vprev = v;          // v0
    float yfin  = y0, vfin = v;
    int   kend  = NMAX;       // last row actually computed

    for (int k = 1; k <= NMAX; ++k) {
        float dk, vk;
        mlp_joint(dwy, du1, dw2, vwy, vu1, vw2, y, db2, vb2, dk, vk);
        if (lane == 0) {
            yout[(size_t)k * n + b] = y;
            vout[(size_t)k * n + b] = vk;
        }
        yfin = y; vfin = vk;
        if (k >= 2 && vk >= vprev) { kend = k; break; }   // ref: break when i>0 && v_new >= v_prev
        vprev = vk;
        y += dk;               // speculative de-eval consumed only on continue
    }

    // ---- frozen rows: lanes store in parallel ----
    const int r = kend + 1 + lane;
    if (r <= NMAX) {
        yout[(size_t)r * n + b] = yfin;
        vout[(size_t)r * n + b] = vfin;
    }
}

extern "C" void kernel_launch(void* const* d_in, const int* in_sizes, int n_in,
                              void* d_out, int out_size, void* d_ws, size_t ws_size,
                              hipStream_t stream) {
    const float* X      = (const float*)d_in[0];
    const float* Y      = (const float*)d_in[1];
    const float* de_W1  = (const float*)d_in[2];
    const float* de_b1  = (const float*)d_in[3];
    const float* de_W2  = (const float*)d_in[4];
    const float* de_b2  = (const float*)d_in[5];
    const float* val_W1 = (const float*)d_in[6];
    const float* val_b1 = (const float*)d_in[7];
    const float* val_W2 = (const float*)d_in[8];
    const float* val_b2 = (const float*)d_in[9];
    float* out = (float*)d_out;

    const int n = in_sizes[0];               // 16384 samples
    dim3 block(64);                           // 1 wave per block -> independent retire
    dim3 grid(n);
    hipLaunchKernelGGL(rmodel_kernel, grid, block, 0, stream,
                       X, Y, de_W1, de_b1, de_W2, de_b2,
                       val_W1, val_b1, val_W2, val_b2, out, n);
}

// Round 4
// 79.225 us; speedup vs baseline: 1.4452x; 1.0684x over previous
//
#include <hip/hip_runtime.h>

#define NMAX 10
#define KPL  16          // hidden units per lane (1024 / 64)
#define L2E  1.4426950408889634f

// ---------- DPP cross-lane sum (VALU pipe only) ----------
template<int CTRL, int RMASK, int BMASK>
__device__ __forceinline__ float dppmov(float v) {
    return __int_as_float(__builtin_amdgcn_update_dpp(
        0, __float_as_int(v), CTRL, RMASK, BMASK, true));
}
__device__ __forceinline__ float rdlane63(float v) {
    return __int_as_float(__builtin_amdgcn_readlane(__float_as_int(v), 63));
}

// two independent wave64 sums -> uniform scalars (2 chains for ILP)
__device__ __forceinline__ void wred2(float& a, float& b) {
    a += dppmov<0xB1, 0xf, 0xf>(a);  b += dppmov<0xB1, 0xf, 0xf>(b);  // quad xor1
    a += dppmov<0x4E, 0xf, 0xf>(a);  b += dppmov<0x4E, 0xf, 0xf>(b);  // quad xor2
    a += dppmov<0x141,0xf, 0xf>(a);  b += dppmov<0x141,0xf, 0xf>(b);  // half-row mirror
    a += dppmov<0x140,0xf, 0xf>(a);  b += dppmov<0x140,0xf, 0xf>(b);  // row mirror
    a += dppmov<0x142,0xa, 0xf>(a);  b += dppmov<0x142,0xa, 0xf>(b);  // row_bcast15
    a += dppmov<0x143,0xc, 0xf>(a);  b += dppmov<0x143,0xc, 0xf>(b);  // row_bcast31
    a = rdlane63(a);                 b = rdlane63(b);
}
__device__ __forceinline__ float wred1(float a) {
    a += dppmov<0xB1, 0xf, 0xf>(a);
    a += dppmov<0x4E, 0xf, 0xf>(a);
    a += dppmov<0x141,0xf, 0xf>(a);
    a += dppmov<0x140,0xf, 0xf>(a);
    a += dppmov<0x142,0xa, 0xf>(a);
    a += dppmov<0x143,0xc, 0xf>(a);
    return rdlane63(a);
}

// elu(p) = s(p) - 1,  s = (p>0 ? p+1 : exp(p)).
// With u1 = u+1 pre-hoisted: p1 = fma(wy,y,u1) = p+1; s = (p1>1 ? p1 : exp2((p1-1)*L2E)).
// The "-1" is folded into the output bias:  bias' = b2 - sum_h(w2[h]).
__device__ __forceinline__ float sact(float p1) {
    float e = __builtin_amdgcn_exp2f(fmaf(p1, L2E, -L2E));
    return p1 > 1.f ? p1 : e;
}

// joint eval of BOTH MLPs at the same y (2 independent chains of 16 units each)
__device__ __forceinline__ void mlp_joint(
    const float (&dwy)[KPL], const float (&du1)[KPL], const float (&dw2)[KPL],
    const float (&vwy)[KPL], const float (&vu1)[KPL], const float (&vw2)[KPL],
    float y, float dbias, float vbias, float& dout, float& vout)
{
    float a0 = 0.f, a1 = 0.f, b0 = 0.f, b1 = 0.f;
#pragma unroll
    for (int k = 0; k < KPL; k += 2) {
        float pd0 = fmaf(dwy[k],     y, du1[k]);
        float pv0 = fmaf(vwy[k],     y, vu1[k]);
        float pd1 = fmaf(dwy[k + 1], y, du1[k + 1]);
        float pv1 = fmaf(vwy[k + 1], y, vu1[k + 1]);
        a0 = fmaf(dw2[k],     sact(pd0), a0);
        b0 = fmaf(vw2[k],     sact(pv0), b0);
        a1 = fmaf(dw2[k + 1], sact(pd1), a1);
        b1 = fmaf(vw2[k + 1], sact(pv1), b1);
    }
    float a = a0 + a1, b = b0 + b1;
    wred2(a, b);
    dout = a + dbias; vout = b + vbias;
}

__global__ __launch_bounds__(256) void rmodel_kernel(
    const float* __restrict__ X, const float* __restrict__ Y,
    const float* __restrict__ de_W1, const float* __restrict__ de_b1,
    const float* __restrict__ de_W2, const float* __restrict__ de_b2,
    const float* __restrict__ val_W1, const float* __restrict__ val_b1,
    const float* __restrict__ val_W2, const float* __restrict__ val_b2,
    float* __restrict__ out, int n)
{
    const int wid  = threadIdx.x >> 6;
    const int lane = threadIdx.x & 63;
    const int b    = blockIdx.x * 4 + wid;   // 4 consecutive samples per block
    if (b >= n) return;

    float dwy[KPL], du1[KPL], dw2[KPL];
    float vwy[KPL], vu1[KPL], vw2[KPL];

    const float x  = X[b];
    const float y0 = Y[b];

    float sw_d = 0.f, sw_v = 0.f;            // sum of W2 (for the folded -1)
#pragma unroll
    for (int k = 0; k < KPL; ++k) {
        const int h = k * 64 + lane;
        float2 w1d = reinterpret_cast<const float2*>(de_W1)[h];
        dwy[k] = w1d.y;
        du1[k] = fmaf(w1d.x, x, de_b1[h]) + 1.f;   // u + 1
        dw2[k] = de_W2[h];   sw_d += dw2[k];
        float2 w1v = reinterpret_cast<const float2*>(val_W1)[h];
        vwy[k] = w1v.y;
        vu1[k] = fmaf(w1v.x, x, val_b1[h]) + 1.f;
        vw2[k] = val_W2[h];  sw_v += vw2[k];
    }
    const float db2 = de_b2[0]  - wred1(sw_d);     // bias' = b2 - sum(w2)
    const float vb2 = val_b2[0] - wred1(sw_v);

    float* __restrict__ yout = out;                       // [NMAX+1][n]
    float* __restrict__ vout = out + (size_t)(NMAX + 1) * n;

    // ---- pipelined chain: each step jointly computes val(y_k) and de(y_k) ----
    float d, v;
    mlp_joint(dwy, du1, dw2, vwy, vu1, vw2, y0, db2, vb2, d, v);   // de(y0), v0
    if (lane == 0) { yout[b] = y0; vout[b] = v; }

    float y     = y0 + d;     // y1
    float vprev = v;          // v0
    float yfin  = y0, vfin = v;
    int   kend  = NMAX;       // last row actually computed

    for (int k = 1; k <= NMAX; ++k) {
        float dk, vk;
        mlp_joint(dwy, du1, dw2, vwy, vu1, vw2, y, db2, vb2, dk, vk);
        if (lane == 0) {
            yout[(size_t)k * n + b] = y;
            vout[(size_t)k * n + b] = vk;
        }
        yfin = y; vfin = vk;
        if (k >= 2 && vk >= vprev) { kend = k; break; }   // ref: break when i>0 && v_new >= v_prev
        vprev = vk;
        y += dk;               // speculative de-eval consumed only on continue
    }

    // ---- frozen rows: lanes store in parallel ----
    const int r = kend + 1 + lane;
    if (r <= NMAX) {
        yout[(size_t)r * n + b] = yfin;
        vout[(size_t)r * n + b] = vfin;
    }
}

extern "C" void kernel_launch(void* const* d_in, const int* in_sizes, int n_in,
                              void* d_out, int out_size, void* d_ws, size_t ws_size,
                              hipStream_t stream) {
    const float* X      = (const float*)d_in[0];
    const float* Y      = (const float*)d_in[1];
    const float* de_W1  = (const float*)d_in[2];
    const float* de_b1  = (const float*)d_in[3];
    const float* de_W2  = (const float*)d_in[4];
    const float* de_b2  = (const float*)d_in[5];
    const float* val_W1 = (const float*)d_in[6];
    const float* val_b1 = (const float*)d_in[7];
    const float* val_W2 = (const float*)d_in[8];
    const float* val_b2 = (const float*)d_in[9];
    float* out = (float*)d_out;

    const int n = in_sizes[0];               // 16384 samples
    dim3 block(256);                          // 4 waves/block, 1 wave = 1 sample
    dim3 grid((n + 3) / 4);
    hipLaunchKernelGGL(rmodel_kernel, grid, block, 0, stream,
                       X, Y, de_W1, de_b1, de_W2, de_b2,
                       val_W1, val_b1, val_W2, val_b2, out, n);
}